// Round 1
// baseline (237.063 us; speedup 1.0000x reference)
//
#include <hip/hip_runtime.h>
#include <hip/hip_bf16.h>
#include <math.h>

#define N_NODES   15000
#define N_EDGES   60000
#define EVOCAB    54
#define NODE_INDIM 64
#define EDGE_INDIM 32
#define H  32
#define EH 64
#define N_BOND 4

// ---------------------------------------------------------------------------
// Kernel A: per-VOCAB edge weight matrices. W_edge depends only on edge_ids
// (54 distinct values), so build a 54 x 32 x 32 table once (221 KB) instead of
// the reference's 60000 x 32 x 32 (245 MB) tensor.
// ---------------------------------------------------------------------------
__global__ void edge_vocab_kernel(const float* __restrict__ edge_table,
                                  const float* __restrict__ e1_W1, const float* __restrict__ e1_b1,
                                  const float* __restrict__ e1_W2, const float* __restrict__ e1_b2,
                                  const float* __restrict__ e2_W1, const float* __restrict__ e2_b1,
                                  const float* __restrict__ e2_W2, const float* __restrict__ e2_b2,
                                  float* __restrict__ W_vocab) {
    int v = blockIdx.x;
    const float* W1 = (v < N_BOND) ? e1_W1 : e2_W1;
    const float* b1 = (v < N_BOND) ? e1_b1 : e2_b1;
    const float* W2 = (v < N_BOND) ? e1_W2 : e2_W2;
    const float* b2 = (v < N_BOND) ? e1_b2 : e2_b2;
    __shared__ float efs[EDGE_INDIM];
    __shared__ float zs[EH];
    int t = threadIdx.x;
    if (t < EDGE_INDIM) efs[t] = edge_table[v * EDGE_INDIM + t];
    __syncthreads();
    if (t < EH) {
        float acc = b1[t];
        #pragma unroll
        for (int j = 0; j < EDGE_INDIM; ++j) acc += efs[j] * W1[t * EDGE_INDIM + j];
        zs[t] = fmaxf(acc, 0.f);
    }
    __syncthreads();
    for (int o = t; o < H * H; o += blockDim.x) {
        float acc = b2[o];
        const float* w = W2 + o * EH;
        #pragma unroll
        for (int k = 0; k < EH; ++k) acc += zs[k] * w[k];
        W_vocab[v * H * H + o] = acc;   // layout [v][i][o] flat = reference reshape
    }
}

// ---------------------------------------------------------------------------
// Kernel B: h0 = relu(node_table[node_ids] @ proj_W.T + proj_b)
// 8 nodes / 256-thread block; proj_W staged in LDS with +1 pad (stride 65)
// so lanes o reading Wl[o*65+j] hit distinct banks.
// ---------------------------------------------------------------------------
__global__ void node_proj_kernel(const int* __restrict__ node_ids,
                                 const float* __restrict__ node_table,
                                 const float* __restrict__ proj_W,
                                 const float* __restrict__ proj_b,
                                 float* __restrict__ h) {
    __shared__ float Wl[H * (NODE_INDIM + 1)];   // padded stride 65
    __shared__ float nfl[8][NODE_INDIM];
    int t = threadIdx.x;
    for (int i = t; i < H * NODE_INDIM; i += 256)
        Wl[(i / NODE_INDIM) * (NODE_INDIM + 1) + (i % NODE_INDIM)] = proj_W[i];
    int ln = t >> 5, o = t & 31;
    int node = blockIdx.x * 8 + ln;                 // 15000 = 1875*8 exact
    int gid = node_ids[node];
    nfl[ln][o]      = node_table[gid * NODE_INDIM + o];
    nfl[ln][o + 32] = node_table[gid * NODE_INDIM + o + 32];
    __syncthreads();
    float acc = proj_b[o];
    #pragma unroll
    for (int j = 0; j < NODE_INDIM; ++j)
        acc += nfl[ln][j] * Wl[o * (NODE_INDIM + 1) + j];
    h[node * H + o] = fmaxf(acc, 0.f);
}

// ---------------------------------------------------------------------------
// attn: ex[e] = exp(leaky_relu(h[src].w_l + h[dst].w_r)); sm[dst] += ex
// (segment-max subtraction skipped: logits are O(1), exp is safe in fp32 and
// alpha = ex/sum is mathematically identical)
// 32 lanes per edge, xor-shuffle reduction within the 32-lane group.
// ---------------------------------------------------------------------------
__global__ void attn_kernel(const int* __restrict__ src, const int* __restrict__ dst,
                            const float* __restrict__ h, const float* __restrict__ attn_w,
                            float* __restrict__ ex, float* __restrict__ sm) {
    int t = threadIdx.x;
    int sub = t >> 5, lane = t & 31;
    int e = blockIdx.x * 8 + sub;                  // 60000 = 7500*8 exact
    int s = src[e], d = dst[e];
    float val = h[s * H + lane] * attn_w[lane] + h[d * H + lane] * attn_w[H + lane];
    #pragma unroll
    for (int k = 16; k > 0; k >>= 1) val += __shfl_xor(val, k, 32);
    if (lane == 0) {
        float a = (val > 0.f) ? val : 0.01f * val;   // leaky_relu slope 0.01
        float ee = expf(a);
        ex[e] = ee;
        atomicAdd(&sm[d], ee);
    }
}

// ---------------------------------------------------------------------------
// msg: agg[dst] += alpha * (h[src] @ W_vocab[edge_id])
// lane o owns output column o; W[i*32+o] reads are coalesced across lanes;
// h_src broadcast via __shfl within the 32-lane group.
// ---------------------------------------------------------------------------
__global__ void msg_kernel(const int* __restrict__ src, const int* __restrict__ dst,
                           const int* __restrict__ edge_ids,
                           const float* __restrict__ h, const float* __restrict__ W_vocab,
                           const float* __restrict__ ex, const float* __restrict__ sm,
                           float* __restrict__ agg) {
    int t = threadIdx.x;
    int sub = t >> 5, o = t & 31;
    int e = blockIdx.x * 8 + sub;
    int s = src[e], d = dst[e], v = edge_ids[e];
    float hv = h[s * H + o];
    const float* W = W_vocab + v * H * H;
    float y = 0.f;
    #pragma unroll
    for (int i = 0; i < H; ++i)
        y += __shfl(hv, i, 32) * W[i * H + o];
    float alpha = ex[e] / sm[d];
    atomicAdd(&agg[d * H + o], alpha * y);
}

// ---------------------------------------------------------------------------
// GRU step: h_out = GRU(relu(agg), h_in). 8 nodes/block, lane o = channel.
// Weights staged in LDS with row stride 33 (pad +1) -> Wi[o*33+j] is
// conflict-free across lanes (bank = (o+j)&31).
// ---------------------------------------------------------------------------
__global__ void gru_kernel(const float* __restrict__ agg,
                           const float* __restrict__ h_in,
                           const float* __restrict__ gWih, const float* __restrict__ gWhh,
                           const float* __restrict__ gbih, const float* __restrict__ gbhh,
                           float* __restrict__ h_out) {
    __shared__ float Wi[3 * H * (H + 1)];   // 96 rows, stride 33
    __shared__ float Wh[3 * H * (H + 1)];
    __shared__ float mt[8][H];
    __shared__ float ht[8][H];
    int t = threadIdx.x;
    for (int i = t; i < 3 * H * H; i += 256) {
        int r = i / H, c = i % H;
        Wi[r * (H + 1) + c] = gWih[i];
        Wh[r * (H + 1) + c] = gWhh[i];
    }
    int ln = t >> 5, o = t & 31;
    int node = blockIdx.x * 8 + ln;
    float m  = fmaxf(agg[node * H + o], 0.f);
    float hv = h_in[node * H + o];
    mt[ln][o] = m;
    ht[ln][o] = hv;
    __syncthreads();
    float gir = 0.f, giz = 0.f, gin = 0.f, ghr = 0.f, ghz = 0.f, ghn = 0.f;
    #pragma unroll
    for (int j = 0; j < H; ++j) {
        float mj = mt[ln][j], hj = ht[ln][j];
        gir += mj * Wi[(o)         * (H + 1) + j];
        giz += mj * Wi[(H + o)     * (H + 1) + j];
        gin += mj * Wi[(2 * H + o) * (H + 1) + j];
        ghr += hj * Wh[(o)         * (H + 1) + j];
        ghz += hj * Wh[(H + o)     * (H + 1) + j];
        ghn += hj * Wh[(2 * H + o) * (H + 1) + j];
    }
    float r = 1.f / (1.f + expf(-(gir + gbih[o]         + ghr + gbhh[o])));
    float z = 1.f / (1.f + expf(-(giz + gbih[H + o]     + ghz + gbhh[H + o])));
    float n = tanhf(gin + gbih[2 * H + o] + r * (ghn + gbhh[2 * H + o]));
    h_out[node * H + o] = (1.f - z) * n + z * hv;
}

// ---------------------------------------------------------------------------
extern "C" void kernel_launch(void* const* d_in, const int* in_sizes, int n_in,
                              void* d_out, int out_size, void* d_ws, size_t ws_size,
                              hipStream_t stream) {
    const int*   node_ids   = (const int*)d_in[0];
    const int*   edge_ids   = (const int*)d_in[1];
    const int*   src        = (const int*)d_in[2];
    const int*   dst        = (const int*)d_in[3];
    const float* node_table = (const float*)d_in[4];
    const float* edge_table = (const float*)d_in[5];
    const float* proj_W     = (const float*)d_in[6];
    const float* proj_b     = (const float*)d_in[7];
    const float* attn_w     = (const float*)d_in[8];
    const float* e1_W1      = (const float*)d_in[9];
    const float* e1_b1      = (const float*)d_in[10];
    const float* e1_W2      = (const float*)d_in[11];
    const float* e1_b2      = (const float*)d_in[12];
    const float* e2_W1      = (const float*)d_in[13];
    const float* e2_b1      = (const float*)d_in[14];
    const float* e2_W2      = (const float*)d_in[15];
    const float* e2_b2      = (const float*)d_in[16];
    const float* gWih       = (const float*)d_in[17];
    const float* gWhh       = (const float*)d_in[18];
    const float* gbih       = (const float*)d_in[19];
    const float* gbhh       = (const float*)d_in[20];

    // workspace layout (all fp32, ~4.4 MB total)
    char* ws = (char*)d_ws;
    float* W_vocab = (float*)(ws);                         // 54*1024*4   = 221184 B
    float* h       = (float*)(ws + 221184);                // 15000*32*4  = 1920000 B
    float* agg     = (float*)(ws + 221184 + 1920000);      // 1920000 B
    float* sm      = (float*)(ws + 221184 + 3840000);      // 60000 B (adjacent to agg)
    float* ex      = (float*)(ws + 221184 + 3900000);      // 240000 B

    edge_vocab_kernel<<<EVOCAB, 256, 0, stream>>>(
        edge_table, e1_W1, e1_b1, e1_W2, e1_b2, e2_W1, e2_b1, e2_W2, e2_b2, W_vocab);
    node_proj_kernel<<<N_NODES / 8, 256, 0, stream>>>(
        node_ids, node_table, proj_W, proj_b, h);

    for (int step = 0; step < 3; ++step) {
        // zero agg (1,920,000 B) + sm (60,000 B) in one contiguous memset
        hipMemsetAsync(agg, 0, 1920000 + 60000, stream);
        attn_kernel<<<N_EDGES / 8, 256, 0, stream>>>(src, dst, h, attn_w, ex, sm);
        msg_kernel<<<N_EDGES / 8, 256, 0, stream>>>(src, dst, edge_ids, h, W_vocab, ex, sm, agg);
        float* hout = (step == 2) ? (float*)d_out : h;
        gru_kernel<<<N_NODES / 8, 256, 0, stream>>>(agg, h, gWih, gWhh, gbih, gbhh, hout);
    }
}